// Round 6
// baseline (160.107 us; speedup 1.0000x reference)
//
#include <hip/hip_runtime.h>
#include <float.h>

typedef _Float16 half8 __attribute__((ext_vector_type(8)));
typedef float    f32x4 __attribute__((ext_vector_type(4)));

// Problem constants
constexpr int N_TOK = 65536;        // 16*64*64 tokens
constexpr int D     = 64;           // embedding dim
constexpr int K     = 2048;         // codebook size
constexpr int TILE_C = 64;          // codes per tile
constexpr int NTILE  = K / TILE_C;  // 32
constexpr int TOK_PER_BLK = 128;    // tokens per fused block (8 waves x 16)
constexpr int NBLK = N_TOK / TOK_PER_BLK;    // 512 fused blocks
constexpr float EPS_RESCORE = 2e-3f; // belt >> pruner err (~1e-4) + key quant (~2.4e-4)

// Output layout (all float32, concatenated in reference return order)
constexpr size_t QN       = (size_t)N_TOK * D;
constexpr size_t SCAL_OFF = QN;
constexpr size_t IDX_OFF  = QN + 5;
constexpr size_t PROB_OFF = IDX_OFF + N_TOK;

// Workspace layout (bytes)
constexpr size_t WS_HNORM = 0;                          // [K] f32  0.5*||c||^2
constexpr size_t WS_COUNT = 8192;                       // [K] u32
constexpr size_t WS_BSUM  = 16384;                      // [NBLK] double
constexpr size_t WS_SW    = 16384 + (size_t)NBLK * 8;   // [NTILE][16][64] half8 staging image

__device__ inline unsigned long long pack_key(float d, int k) {
    unsigned u = __float_as_uint(d);
    u = (u & 0x80000000u) ? ~u : (u | 0x80000000u);   // monotone float->uint
    return ((unsigned long long)u << 32) | (unsigned)k;
}

__device__ inline float unpack_dist(unsigned long long key) {
    unsigned u = (unsigned)(key >> 32);
    u = (u & 0x80000000u) ? (u & 0x7FFFFFFFu) : ~u;   // inverse monotone map
    return __uint_as_float(u);
}

__device__ inline unsigned long long shfl_xor_u64_w16(unsigned long long v, int m) {
    int lo = __shfl_xor((int)(unsigned)v, m, 16);
    int hi = __shfl_xor((int)(unsigned)(v >> 32), m, 16);
    return ((unsigned long long)(unsigned)hi << 32) | (unsigned)lo;
}

// async global->LDS, 16 B per lane, dest = lds_base + lane*16
__device__ inline void load16_to_lds(const void* g, void* l) {
    __builtin_amdgcn_global_load_lds(
        (const __attribute__((address_space(1))) void*)g,
        (__attribute__((address_space(3))) void*)l, 16, 0, 0);
}

// One thread per (code row r, 8-elem chunk c0). Staging image: per tile,
// 16 chunks of 64 half8; chunk index = slot*4 + cg, element = consumer lane.
//   sw[(t*16 + s*4 + cg)*64 + lane]
// Consumer lane l (g=l>>4, m16=l&15) at col-group cg reads slots s=0..3 =
// {hi chunk g, hi chunk g+4, lo chunk g, lo chunk g+4} for code cg*16+m16.
// Producer (r, c0): cg=(r>>4)&3, lane=(c0&3)*16+(r&15), s = c0>>2 (hi) or
// 2+(c0>>2) (lo). global_load_lds linear dest reproduces this exactly, and
// every ds_read_b128 is 64 lanes x contiguous 16 B -> conflict-free.
__global__ __launch_bounds__(256) void vq_init(const float* __restrict__ emb,
                                               float* __restrict__ hnorm,
                                               unsigned* __restrict__ counts,
                                               double* __restrict__ blocksums,
                                               half8* __restrict__ sw) {
    const int g  = blockIdx.x * 256 + threadIdx.x;   // 0..16383
    const int r  = g >> 3;                           // code row
    const int c0 = g & 7;                            // chunk within row
    const float4* p4 = (const float4*)(emb + (size_t)r * D + 8 * c0);
    float4 q0 = p4[0], q1 = p4[1];
    float v[8] = {q0.x, q0.y, q0.z, q0.w, q1.x, q1.y, q1.z, q1.w};
    half8 h, l;
    float s = 0.f;
#pragma unroll
    for (int i = 0; i < 8; ++i) {
        s += v[i] * v[i];
        _Float16 hh = (_Float16)v[i];
        h[i] = hh;
        l[i] = (_Float16)(v[i] - (float)hh);
    }
    const int t    = r >> 6;
    const int cg   = (r >> 4) & 3;
    const int m16  = r & 15;
    const int lane = (c0 & 3) * 16 + m16;
    const int sh   = c0 >> 2;
    sw[((size_t)(t * 16 + sh * 4 + cg)) * 64 + lane]       = h;  // hi
    sw[((size_t)(t * 16 + (2 + sh) * 4 + cg)) * 64 + lane] = l;  // lo

#pragma unroll
    for (int off = 1; off < 8; off <<= 1) s += __shfl_xor(s, off, 8);
    if (c0 == 0) hnorm[r] = 0.5f * s;
    if (g < K) counts[g] = 0u;
    if (g < NBLK) blocksums[g] = 0.0;
}

// read col-group CG's 4 fragments from the staged tile (conflict-free b128)
#define LDSB(CUR, CG, P0, P1, P2, P3)                                              \
  {                                                                                \
    const half8* _bp = &buf[CUR][(CG) * 64 + lane];                                \
    P0 = _bp[0]; P1 = _bp[256]; P2 = _bp[512]; P3 = _bp[768];                      \
  }

// 6 chained MFMAs for one col-group; hn added at the end (1 extra VALU/elem,
// ~1 ulp rounding change). Min-tracking packs the 5-bit tile index into the
// low mantissa bits (perturbation <= 32 ulp ~ 2.4e-4 << belt).
#define VQ_CG(P0, P1, P2, P3, HN, CG)                                              \
  {                                                                                \
    f32x4 acc = {0.f, 0.f, 0.f, 0.f};                                              \
    __builtin_amdgcn_s_setprio(1);                                                 \
    acc = __builtin_amdgcn_mfma_f32_16x16x32_f16(axh0, P0, acc, 0, 0, 0);          \
    acc = __builtin_amdgcn_mfma_f32_16x16x32_f16(axh1, P1, acc, 0, 0, 0);          \
    acc = __builtin_amdgcn_mfma_f32_16x16x32_f16(axl0, P0, acc, 0, 0, 0);          \
    acc = __builtin_amdgcn_mfma_f32_16x16x32_f16(axl1, P1, acc, 0, 0, 0);          \
    acc = __builtin_amdgcn_mfma_f32_16x16x32_f16(axh0, P2, acc, 0, 0, 0);          \
    acc = __builtin_amdgcn_mfma_f32_16x16x32_f16(axh1, P3, acc, 0, 0, 0);          \
    __builtin_amdgcn_s_setprio(0);                                                 \
    _Pragma("unroll")                                                              \
    for (int r = 0; r < 4; ++r) {                                                  \
      float _d = acc[r] + (HN);                                                    \
      unsigned _kb = (__float_as_uint(_d) & 0xFFFFFFE0u) | (unsigned)t;            \
      best_d[CG][r] = fminf(best_d[CG][r], __uint_as_float(_kb));                  \
    }                                                                              \
  }

// Fused: one block = 128 tokens (8 waves x 16-token a-tile) x ALL 2048 codes.
// Waves split TOKENS, so every staged 16 KB code tile is consumed by all 8
// waves (192 MFMAs per stage vs 96 in R4) -> B-bytes-per-MFMA halved (the
// R4->R5 experiments isolated this as the binding resource). B comes from
// LDS (double-buffered, staged via global_load_lds a full tile ahead of the
// barrier drain); hnorm prefetched into registers one tile ahead -> no
// vmcnt waits inside an iteration.
__global__ __launch_bounds__(512) void vq_fused(const float* __restrict__ x,
                                                const float* __restrict__ emb,
                                                const float* __restrict__ hnorm,
                                                const half8* __restrict__ sw,
                                                unsigned* __restrict__ counts,
                                                double* __restrict__ blocksums,
                                                float* __restrict__ out) {
    __shared__ half8 buf[2][1024];      // 2 x 16 KB staged code tiles
    __shared__ int bks[TOK_PER_BLK];
    __shared__ double wsum[8];

    const int tid  = threadIdx.x;
    const int lane = tid & 63;
    const int wav  = tid >> 6;          // 0..7: a-tile owner
    const int t0   = blockIdx.x * TOK_PER_BLK;
    const int m16  = lane & 15;
    const int g    = lane >> 4;
    const int ko   = g * 8;

    // A fragments: this wave's 16 tokens, negated hi/lo fp16 split
    half8 axh0, axh1, axl0, axl1;
    {
        const float* xr = x + (size_t)(t0 + wav * 16 + m16) * D;
#pragma unroll
        for (int c = 0; c < 2; ++c) {
            const float4* p4 = (const float4*)(xr + 32 * c + ko);
            float4 q0 = p4[0], q1 = p4[1];
            float v[8] = {q0.x, q0.y, q0.z, q0.w, q1.x, q1.y, q1.z, q1.w};
            half8 h, l;
#pragma unroll
            for (int j = 0; j < 8; ++j) {
                float nv = -v[j];
                _Float16 hh = (_Float16)nv;
                h[j] = hh;
                l[j] = (_Float16)(nv - (float)hh);
            }
            if (c == 0) { axh0 = h; axl0 = l; } else { axh1 = h; axl1 = l; }
        }
    }

    float best_d[4][4];                 // [col-group][r] packed keys
#pragma unroll
    for (int cg = 0; cg < 4; ++cg)
#pragma unroll
        for (int r = 0; r < 4; ++r) best_d[cg][r] = FLT_MAX;

    // hnorm prefetch (tile 0) -- lane's code col at cg is cg*16+m16
    const float* hnb = hnorm + m16;
    float hn_nxt[4];
#pragma unroll
    for (int cg = 0; cg < 4; ++cg) hn_nxt[cg] = hnb[cg * 16];

    // prologue: stage tile 0 into buf[0] (wave stages chunks 2w, 2w+1)
    {
        const half8* src = sw + (size_t)(2 * wav) * 64 + lane;
        load16_to_lds(src,      &buf[0][(2 * wav) * 64]);
        load16_to_lds(src + 64, &buf[0][(2 * wav + 1) * 64]);
    }
    __syncthreads();

    for (int t = 0; t < NTILE; ++t) {
        const int cur = t & 1;
        const float hn0 = hn_nxt[0], hn1 = hn_nxt[1];
        const float hn2 = hn_nxt[2], hn3 = hn_nxt[3];
        if (t + 1 < NTILE) {            // prefetch hnorm + stage next tile
            const float* hb = hnb + (t + 1) * 64;
            hn_nxt[0] = hb[0];  hn_nxt[1] = hb[16];
            hn_nxt[2] = hb[32]; hn_nxt[3] = hb[48];
            const half8* src = sw + ((size_t)(t + 1) * 16 + 2 * wav) * 64 + lane;
            load16_to_lds(src,      &buf[cur ^ 1][(2 * wav) * 64]);
            load16_to_lds(src + 64, &buf[cur ^ 1][(2 * wav + 1) * 64]);
        }
        half8 e0, e1, e2, e3, o0, o1, o2, o3;
        LDSB(cur, 0, e0, e1, e2, e3);
        LDSB(cur, 1, o0, o1, o2, o3);
        VQ_CG(e0, e1, e2, e3, hn0, 0);
        LDSB(cur, 2, e0, e1, e2, e3);
        VQ_CG(o0, o1, o2, o3, hn1, 1);
        LDSB(cur, 3, o0, o1, o2, o3);
        VQ_CG(e0, e1, e2, e3, hn2, 2);
        VQ_CG(o0, o1, o2, o3, hn3, 3);
        __syncthreads();   // readers of cur done; staged cur^1 drained
    }

    // per-wave merge: token = wav*16 + g*4 + r lives in 16 lanes (m16 cols)
#pragma unroll
    for (int r = 0; r < 4; ++r) {
        unsigned long long key = ~0ULL;       // lane-local min over col-groups
#pragma unroll
        for (int cg = 0; cg < 4; ++cg) {
            const unsigned bits = __float_as_uint(best_d[cg][r]);
            const int code = (int)(bits & 31u) * TILE_C + cg * 16 + m16;
            const unsigned long long kk = pack_key(best_d[cg][r], code);
            if (kk < key) key = kk;
        }
        unsigned long long kmin = key;        // butterfly over 16-lane group
#pragma unroll
        for (int off = 8; off; off >>= 1) {
            unsigned long long o = shfl_xor_u64_w16(kmin, off);
            if (o < kmin) kmin = o;
        }
        const float fmin = unpack_dist(kmin);
        const bool fl = unpack_dist(key) <= fmin + EPS_RESCORE;
        const unsigned long long bal = __ballot(fl);
        const int cnt = (int)__popcll((bal >> (g * 16)) & 0xFFFFull);
        if (cnt > 1) {   // near-tie: wave-parallel exact fp32 rescore
            unsigned long long ex = ~0ULL;
            if (fl) {
                const int k = (int)(unsigned)(key & 0xFFFFFFFFu);
                const float* xr = x + (size_t)(t0 + wav * 16 + g * 4 + r) * D;
                const float* cr = emb + (size_t)k * D;
                float s0 = 0.f, s1 = 0.f, s2 = 0.f, s3 = 0.f;
#pragma unroll
                for (int i = 0; i < 16; ++i) {
                    s0 = fmaf(cr[4 * i + 0], xr[4 * i + 0], s0);
                    s1 = fmaf(cr[4 * i + 1], xr[4 * i + 1], s1);
                    s2 = fmaf(cr[4 * i + 2], xr[4 * i + 2], s2);
                    s3 = fmaf(cr[4 * i + 3], xr[4 * i + 3], s3);
                }
                ex = pack_key(hnorm[k] - ((s0 + s1) + (s2 + s3)), k);
            }
#pragma unroll
            for (int off = 8; off; off >>= 1) {
                unsigned long long o = shfl_xor_u64_w16(ex, off);
                if (o < ex) ex = o;
            }
            kmin = ex;
        }
        if (m16 == 0) {
            const int bk = (int)(unsigned)(kmin & 0xFFFFFFFFu);
            const int tl = wav * 16 + g * 4 + r;
            bks[tl] = bk;
            out[IDX_OFF + t0 + tl] = (float)bk;
            atomicAdd(&counts[bk], 1u);
        }
    }
    __syncthreads();

    // inline epilogue: quantize + sumsq (4 threads per token, coalesced)
    const int tok = tid >> 2;               // 0..127
    const int i4  = tid & 3;
    const int bk  = bks[tok];
    const float4* xr4 = (const float4*)(x + (size_t)(t0 + tok) * D);
    const float4* cr4 = (const float4*)(emb + (size_t)bk * D);
    float4* qr4 = (float4*)(out + (size_t)(t0 + tok) * D);
    float local = 0.f;
#pragma unroll
    for (int ii = 0; ii < 4; ++ii) {
        const int idx = i4 + 4 * ii;
        float4 xv = xr4[idx];
        float4 cv = cr4[idx];
        float dx = cv.x - xv.x, dy = cv.y - xv.y;
        float dz = cv.z - xv.z, dw = cv.w - xv.w;
        local += dx * dx + dy * dy + dz * dz + dw * dw;
        float4 q;
        q.x = xv.x + dx; q.y = xv.y + dy;   // straight-through: x + (q - x)
        q.z = xv.z + dz; q.w = xv.w + dw;
        qr4[idx] = q;
    }
    double ld = (double)local;
#pragma unroll
    for (int off = 32; off > 0; off >>= 1) ld += __shfl_down(ld, off, 64);
    if (lane == 0) wsum[wav] = ld;
    __syncthreads();
    if (tid == 0) {
        double s2 = 0.0;
#pragma unroll
        for (int w = 0; w < 8; ++w) s2 += wsum[w];
        blocksums[blockIdx.x] = s2;
    }
}

__global__ __launch_bounds__(256) void vq_finalize(const unsigned* __restrict__ counts,
                                                   const double* __restrict__ blocksums,
                                                   float* __restrict__ out) {
    const int tid = threadIdx.x;
    double e = 0.0;
#pragma unroll
    for (int i = 0; i < 8; ++i) {
        int k = tid + i * 256;
        float p = (float)counts[k] / 65536.0f;
        out[PROB_OFF + k] = p;
        double pd = (double)p;
        e += pd * log(pd + 1e-5);
    }
    double s = 0.0;
#pragma unroll
    for (int i = 0; i < NBLK / 256; ++i) s += blocksums[tid + i * 256];
#pragma unroll
    for (int off = 32; off > 0; off >>= 1) {
        e += __shfl_down(e, off, 64);
        s += __shfl_down(s, off, 64);
    }
    __shared__ double we[4], ws2[4];
    int lane = tid & 63, wid = tid >> 6;
    if (lane == 0) { we[wid] = e; ws2[wid] = s; }
    __syncthreads();
    if (tid == 0) {
        double entropy = (we[0] + we[1]) + (we[2] + we[3]);
        double sumsq   = (ws2[0] + ws2[1]) + (ws2[2] + ws2[3]);
        double mse     = sumsq / (double)((size_t)N_TOK * D);
        out[SCAL_OFF + 0] = (float)(1.25 * mse + 0.1 * entropy); // vq_loss
        out[SCAL_OFF + 1] = (float)mse;                          // commitment_loss
        out[SCAL_OFF + 2] = (float)mse;                          // codebook_loss
        out[SCAL_OFF + 3] = (float)exp(-entropy);                // perplexity
        out[SCAL_OFF + 4] = (float)entropy;                      // entropy_loss
    }
}

extern "C" void kernel_launch(void* const* d_in, const int* in_sizes, int n_in,
                              void* d_out, int out_size, void* d_ws, size_t ws_size,
                              hipStream_t stream) {
    const float* x   = (const float*)d_in[0];
    const float* emb = (const float*)d_in[1];
    float* out = (float*)d_out;

    char* ws = (char*)d_ws;
    float*    hnorm     = (float*)(ws + WS_HNORM);
    unsigned* counts    = (unsigned*)(ws + WS_COUNT);
    double*   blocksums = (double*)(ws + WS_BSUM);
    half8*    sw        = (half8*)(ws + WS_SW);

    vq_init<<<K * 8 / 256, 256, 0, stream>>>(emb, hnorm, counts, blocksums, sw);
    vq_fused<<<NBLK, 512, 0, stream>>>(x, emb, hnorm, sw, counts, blocksums, out);
    vq_finalize<<<1, 256, 0, stream>>>(counts, blocksums, out);
}

// Round 7
// 134.216 us; speedup vs baseline: 1.1929x; 1.1929x over previous
//
#include <hip/hip_runtime.h>
#include <float.h>

typedef _Float16 half8 __attribute__((ext_vector_type(8)));
typedef float    f32x4 __attribute__((ext_vector_type(4)));

// Problem constants
constexpr int N_TOK = 65536;        // 16*64*64 tokens
constexpr int D     = 64;           // embedding dim
constexpr int K     = 2048;         // codebook size
constexpr int TILE_C = 64;          // codes per tile
constexpr int NTILE  = K / TILE_C;  // 32
constexpr int TOK_PER_BLK = 64;     // tokens per fused block
constexpr int NBLK = N_TOK / TOK_PER_BLK;    // 1024 fused blocks
constexpr float EPS_RESCORE = 2e-3f; // belt >> pruner error (~1e-4) + key quant (~1.2e-4)

// Output layout (all float32, concatenated in reference return order)
constexpr size_t QN       = (size_t)N_TOK * D;
constexpr size_t SCAL_OFF = QN;
constexpr size_t IDX_OFF  = QN + 5;
constexpr size_t PROB_OFF = IDX_OFF + N_TOK;

// Workspace layout (bytes), total ~537 KB
constexpr size_t WS_HNORM = 0;                          // [K] f32  0.5*||c||^2
constexpr size_t WS_COUNT = 8192;                       // [K] u32
constexpr size_t WS_BSUM  = 16384;                      // [1024] double
constexpr size_t WS_SW    = 24576;                      // [NTILE][256][4] half8 per-lane frag image

__device__ inline unsigned long long pack_key(float d, int k) {
    unsigned u = __float_as_uint(d);
    u = (u & 0x80000000u) ? ~u : (u | 0x80000000u);   // monotone float->uint
    return ((unsigned long long)u << 32) | (unsigned)k;
}

__device__ inline float unpack_dist(unsigned long long key) {
    unsigned u = (unsigned)(key >> 32);
    u = (u & 0x80000000u) ? (u & 0x7FFFFFFFu) : ~u;   // inverse monotone map
    return __uint_as_float(u);
}

__device__ inline unsigned long long shfl_xor_u64_w16(unsigned long long v, int m) {
    int lo = __shfl_xor((int)(unsigned)v, m, 16);
    int hi = __shfl_xor((int)(unsigned)(v >> 32), m, 16);
    return ((unsigned long long)(unsigned)hi << 32) | (unsigned)lo;
}

// One thread per (code row r, 8-elem chunk c0). Frag image: per tile, the 4
// MFMA B-fragments a consumer lane needs are CONTIGUOUS 64 B:
//   sw[(t*256 + tid)*4 + slot]  (half8), consumer tid = w*64+l, g=l>>4,
//   m16=l&15, code = t*64 + w*16 + m16,
//   slots = {hi chunk g, hi chunk g+4, lo chunk g, lo chunk g+4}.
__global__ __launch_bounds__(256) void vq_init(const float* __restrict__ emb,
                                               float* __restrict__ hnorm,
                                               unsigned* __restrict__ counts,
                                               double* __restrict__ blocksums,
                                               half8* __restrict__ sw) {
    const int g  = blockIdx.x * 256 + threadIdx.x;   // 0..16383
    const int r  = g >> 3;                           // code row
    const int c0 = g & 7;                            // chunk within row
    const float4* p4 = (const float4*)(emb + (size_t)r * D + 8 * c0);
    float4 q0 = p4[0], q1 = p4[1];
    float v[8] = {q0.x, q0.y, q0.z, q0.w, q1.x, q1.y, q1.z, q1.w};
    half8 h, l;
    float s = 0.f;
#pragma unroll
    for (int i = 0; i < 8; ++i) {
        s += v[i] * v[i];
        _Float16 hh = (_Float16)v[i];
        h[i] = hh;
        l[i] = (_Float16)(v[i] - (float)hh);
    }
    const int t    = r >> 6;
    const int w    = (r >> 4) & 3;
    const int m16  = r & 15;
    const int lane = (c0 & 3) * 16 + m16;
    const int slot = c0 >> 2;
    half8* dst = sw + ((size_t)(t * 256 + w * 64 + lane)) * 4;
    dst[slot]     = h;   // hi fragment
    dst[2 + slot] = l;   // lo fragment

#pragma unroll
    for (int off = 1; off < 8; off <<= 1) s += __shfl_xor(s, off, 8);
    if (c0 == 0) hnorm[r] = 0.5f * s;
    if (g < K) counts[g] = 0u;
    if (g < NBLK) blocksums[g] = 0.0;
}

// Load tile TT's 4 contiguous B fragments + code half-norm (absolute index,
// ring order). pb0 = sw + tid*4, ph0 = hnorm + cit.
#define LOADB(TT, P0, P1, P2, P3, HN)                                              \
  {                                                                                \
    const half8* _q = pb0 + ((size_t)(TT) << 10);                                  \
    P0 = _q[0]; P1 = _q[1]; P2 = _q[2]; P3 = _q[3];                                \
    HN = ph0[(TT) << 6];                                                           \
  }

// Two independent 3-dep MFMA chains per a-tile (8 streams/wave -> pipe stays
// fed even with large dependent-MFMA latency). No setprio: homogeneous waves
// rely on inter-wave interleaving, which priority-hogging suppresses.
// Min-tracking packs the 5-bit tile index into the low mantissa bits
// (2 VALU/elem; perturbation <= 32 ulp ~ 1.2e-4 << belt).
#define VQ_STEP(P0, P1, P2, P3, HN, TT)                                            \
  {                                                                                \
    _Pragma("unroll")                                                              \
    for (int a = 0; a < 4; ++a) {                                                  \
      f32x4 ac1 = {(HN), (HN), (HN), (HN)};                                        \
      f32x4 ac2 = {0.f, 0.f, 0.f, 0.f};                                            \
      ac1 = __builtin_amdgcn_mfma_f32_16x16x32_f16(axh[a][0], P0, ac1, 0, 0, 0);   \
      ac2 = __builtin_amdgcn_mfma_f32_16x16x32_f16(axh[a][1], P1, ac2, 0, 0, 0);   \
      ac1 = __builtin_amdgcn_mfma_f32_16x16x32_f16(axl[a][0], P0, ac1, 0, 0, 0);   \
      ac2 = __builtin_amdgcn_mfma_f32_16x16x32_f16(axl[a][1], P1, ac2, 0, 0, 0);   \
      ac1 = __builtin_amdgcn_mfma_f32_16x16x32_f16(axh[a][0], P2, ac1, 0, 0, 0);   \
      ac2 = __builtin_amdgcn_mfma_f32_16x16x32_f16(axh[a][1], P3, ac2, 0, 0, 0);   \
      _Pragma("unroll")                                                            \
      for (int r = 0; r < 4; ++r) {                                                \
        float _d = ac1[r] + ac2[r];                                                \
        unsigned _kb = (__float_as_uint(_d) & 0xFFFFFFE0u) | (unsigned)(TT);       \
        best_d[a][r] = fminf(best_d[a][r], __uint_as_float(_kb));                  \
      }                                                                            \
    }                                                                              \
  }

// Fused: one block = 64 tokens x ALL 2048 codes. Barrier-free main loop,
// even/odd register double-buffer, RING tile order: block starts at
// hash(blockIdx)&31 and wraps -- decorrelates block/wave phases and spreads
// L2 traffic over the whole 512 KB frag image (no same-line hotspot).
__global__ __launch_bounds__(256) void vq_fused(const float* __restrict__ x,
                                                const float* __restrict__ emb,
                                                const float* __restrict__ hnorm,
                                                const half8* __restrict__ sw,
                                                unsigned* __restrict__ counts,
                                                double* __restrict__ blocksums,
                                                float* __restrict__ out) {
    __shared__ unsigned long long kls[64][5];         // 4 candidates + pad
    __shared__ int bks[64];
    __shared__ double wsum[4];

    const int tid  = threadIdx.x;
    const int lane = tid & 63;
    const int wav  = tid >> 6;
    const int t0   = blockIdx.x * TOK_PER_BLK;
    const int m16  = lane & 15;             // A row (token) / B col (code)
    const int g    = lane >> 4;             // k-chunk group (0..3)
    const int ko   = g * 8;
    const int cit  = wav * 16 + m16;        // wave w owns codes [w*16, w*16+16)

    // A fragments: 4 a-tiles (the block's 64 tokens), negated hi/lo fp16 split
    half8 axh[4][2], axl[4][2];
#pragma unroll
    for (int a = 0; a < 4; ++a) {
        const float* xr = x + (size_t)(t0 + 16 * a + m16) * D;
#pragma unroll
        for (int c = 0; c < 2; ++c) {
            const float4* p4 = (const float4*)(xr + 32 * c + ko);
            float4 q0 = p4[0], q1 = p4[1];
            float v[8] = {q0.x, q0.y, q0.z, q0.w, q1.x, q1.y, q1.z, q1.w};
            half8 h, l;
#pragma unroll
            for (int j = 0; j < 8; ++j) {
                float nv = -v[j];
                _Float16 hh = (_Float16)nv;
                h[j] = hh;
                l[j] = (_Float16)(nv - (float)hh);
            }
            axh[a][c] = h; axl[a][c] = l;
        }
    }

    float best_d[4][4];                     // packed keys: dist w/ tile idx in low 5 bits
#pragma unroll
    for (int a = 0; a < 4; ++a)
#pragma unroll
        for (int r = 0; r < 4; ++r) best_d[a][r] = FLT_MAX;

    // per-lane streaming bases: 64 B of fragments per lane per tile
    const half8* pb0 = sw + (size_t)tid * 4;          // + tile*1024
    const float* ph0 = hnorm + cit;                   // + tile*64

    // ring start: must differ across blocks that share a CU (same-CU blocks
    // have blockIdx strides ~8/256, so mix higher bits into the low 5)
    const int b = blockIdx.x;
    const int tstart = (b ^ (b >> 5) ^ (b >> 8)) & 31;

    half8 sA0, sA1, sA2, sA3;  float hA;   // even-position tiles
    half8 sB0, sB1, sB2, sB3;  float hB;   // odd-position tiles

    int ttA = tstart;
    LOADB(ttA, sA0, sA1, sA2, sA3, hA);

    for (int i = 0; i < NTILE; i += 2) {
        const int ttB = (tstart + i + 1) & 31;
        LOADB(ttB, sB0, sB1, sB2, sB3, hB);
        VQ_STEP(sA0, sA1, sA2, sA3, hA, ttA);
        const int ttN = (tstart + i + 2) & 31;
        if (i + 2 < NTILE) { LOADB(ttN, sA0, sA1, sA2, sA3, hA); }
        VQ_STEP(sB0, sB1, sB2, sB3, hB, ttB);
        ttA = ttN;
    }

    // recover code from packed key; col-reduce over this wave's 16 columns
#pragma unroll
    for (int a = 0; a < 4; ++a)
#pragma unroll
        for (int r = 0; r < 4; ++r) {
            const unsigned bits = __float_as_uint(best_d[a][r]);
            const int code = (int)(bits & 31u) * TILE_C + cit;
            unsigned long long key = pack_key(best_d[a][r], code);
#pragma unroll
            for (int off = 8; off; off >>= 1) {
                unsigned long long o = shfl_xor_u64_w16(key, off);
                if (o < key) key = o;
            }
            if (m16 == 0) kls[16 * a + g * 4 + r][wav] = key;
        }
    __syncthreads();

    // merge the 4 wave-winners per token (wave 0, one lane per token)
    if (tid < 64) {
        float ds[4]; int kk[4];
        unsigned long long kmin = ~0ULL;
#pragma unroll
        for (int w = 0; w < 4; ++w) {
            unsigned long long key = kls[tid][w];
            ds[w] = unpack_dist(key);
            kk[w] = (int)(unsigned)(key & 0xFFFFFFFFu);
            if (key < kmin) kmin = key;
        }
        int bk = (int)(unsigned)(kmin & 0xFFFFFFFFu);
        const float fmin = unpack_dist(kmin);
        int cnt = 0;
#pragma unroll
        for (int w = 0; w < 4; ++w) cnt += (ds[w] <= fmin + EPS_RESCORE) ? 1 : 0;

        if (cnt > 1) {   // rare near-tie: exact fp32 rescore; packed-key min
            unsigned long long bkey = ~0ULL;   // smaller dist, tie smaller k
            const float* xr = x + (size_t)(t0 + tid) * D;
            for (int w = 0; w < 4; ++w) {
                if (ds[w] <= fmin + EPS_RESCORE) {
                    const int k = kk[w];
                    const float* cr = emb + (size_t)k * D;
                    float s0 = 0.f, s1 = 0.f, s2 = 0.f, s3 = 0.f;
#pragma unroll
                    for (int i = 0; i < 16; ++i) {
                        s0 = fmaf(cr[4 * i + 0], xr[4 * i + 0], s0);
                        s1 = fmaf(cr[4 * i + 1], xr[4 * i + 1], s1);
                        s2 = fmaf(cr[4 * i + 2], xr[4 * i + 2], s2);
                        s3 = fmaf(cr[4 * i + 3], xr[4 * i + 3], s3);
                    }
                    float hd = hnorm[k] - ((s0 + s1) + (s2 + s3));
                    unsigned long long key = pack_key(hd, k);
                    if (key < bkey) bkey = key;
                }
            }
            bk = (int)(unsigned)(bkey & 0xFFFFFFFFu);
        }
        bks[tid] = bk;
        out[IDX_OFF + t0 + tid] = (float)bk;
        atomicAdd(&counts[bk], 1u);
    }
    __syncthreads();

    // inline epilogue: quantize + sumsq (4 threads per token, coalesced)
    const int tok = tid >> 2;
    const int i4  = tid & 3;
    const int bk  = bks[tok];
    const float4* xr4 = (const float4*)(x + (size_t)(t0 + tok) * D);
    const float4* cr4 = (const float4*)(emb + (size_t)bk * D);
    float4* qr4 = (float4*)(out + (size_t)(t0 + tok) * D);
    float local = 0.f;
#pragma unroll
    for (int ii = 0; ii < 4; ++ii) {
        const int idx = i4 + 4 * ii;
        float4 xv = xr4[idx];
        float4 cv = cr4[idx];
        float dx = cv.x - xv.x, dy = cv.y - xv.y;
        float dz = cv.z - xv.z, dw = cv.w - xv.w;
        local += dx * dx + dy * dy + dz * dz + dw * dw;
        float4 q;
        q.x = xv.x + dx; q.y = xv.y + dy;   // straight-through: x + (q - x)
        q.z = xv.z + dz; q.w = xv.w + dw;
        qr4[idx] = q;
    }
    double ld = (double)local;
#pragma unroll
    for (int off = 32; off > 0; off >>= 1) ld += __shfl_down(ld, off, 64);
    if (lane == 0) wsum[wav] = ld;
    __syncthreads();
    if (tid == 0)
        blocksums[blockIdx.x] = (wsum[0] + wsum[1]) + (wsum[2] + wsum[3]);
}

__global__ __launch_bounds__(256) void vq_finalize(const unsigned* __restrict__ counts,
                                                   const double* __restrict__ blocksums,
                                                   float* __restrict__ out) {
    const int tid = threadIdx.x;
    double e = 0.0;
#pragma unroll
    for (int i = 0; i < 8; ++i) {
        int k = tid + i * 256;
        float p = (float)counts[k] / 65536.0f;
        out[PROB_OFF + k] = p;
        double pd = (double)p;
        e += pd * log(pd + 1e-5);
    }
    double s = 0.0;
#pragma unroll
    for (int i = 0; i < NBLK / 256; ++i) s += blocksums[tid + i * 256];
#pragma unroll
    for (int off = 32; off > 0; off >>= 1) {
        e += __shfl_down(e, off, 64);
        s += __shfl_down(s, off, 64);
    }
    __shared__ double we[4], ws2[4];
    int lane = tid & 63, wid = tid >> 6;
    if (lane == 0) { we[wid] = e; ws2[wid] = s; }
    __syncthreads();
    if (tid == 0) {
        double entropy = (we[0] + we[1]) + (we[2] + we[3]);
        double sumsq   = (ws2[0] + ws2[1]) + (ws2[2] + ws2[3]);
        double mse     = sumsq / (double)((size_t)N_TOK * D);
        out[SCAL_OFF + 0] = (float)(1.25 * mse + 0.1 * entropy); // vq_loss
        out[SCAL_OFF + 1] = (float)mse;                          // commitment_loss
        out[SCAL_OFF + 2] = (float)mse;                          // codebook_loss
        out[SCAL_OFF + 3] = (float)exp(-entropy);                // perplexity
        out[SCAL_OFF + 4] = (float)entropy;                      // entropy_loss
    }
}

extern "C" void kernel_launch(void* const* d_in, const int* in_sizes, int n_in,
                              void* d_out, int out_size, void* d_ws, size_t ws_size,
                              hipStream_t stream) {
    const float* x   = (const float*)d_in[0];
    const float* emb = (const float*)d_in[1];
    float* out = (float*)d_out;

    char* ws = (char*)d_ws;
    float*    hnorm     = (float*)(ws + WS_HNORM);
    unsigned* counts    = (unsigned*)(ws + WS_COUNT);
    double*   blocksums = (double*)(ws + WS_BSUM);
    half8*    sw        = (half8*)(ws + WS_SW);

    vq_init<<<K * 8 / 256, 256, 0, stream>>>(emb, hnorm, counts, blocksums, sw);
    vq_fused<<<NBLK, 256, 0, stream>>>(x, emb, hnorm, sw, counts, blocksums, out);
    vq_finalize<<<1, 256, 0, stream>>>(counts, blocksums, out);
}

// Round 8
// 133.497 us; speedup vs baseline: 1.1993x; 1.0054x over previous
//
#include <hip/hip_runtime.h>
#include <float.h>

typedef _Float16 half8 __attribute__((ext_vector_type(8)));
typedef float    f32x4 __attribute__((ext_vector_type(4)));

// Problem constants
constexpr int N_TOK = 65536;        // 16*64*64 tokens
constexpr int D     = 64;           // embedding dim
constexpr int K     = 2048;         // codebook size
constexpr int TILE_C = 64;          // codes per tile
constexpr int NTILE  = K / TILE_C;  // 32
constexpr int TOK_PER_BLK = 64;     // tokens per fused block
constexpr int NBLK = N_TOK / TOK_PER_BLK;    // 1024 fused blocks
constexpr float EPS_RESCORE = 2e-3f; // belt >> pruner error (~1e-4) + key quant (~1.2e-4)

// Output layout (all float32, concatenated in reference return order)
constexpr size_t QN       = (size_t)N_TOK * D;
constexpr size_t SCAL_OFF = QN;
constexpr size_t IDX_OFF  = QN + 5;
constexpr size_t PROB_OFF = IDX_OFF + N_TOK;

// Workspace layout (bytes), total ~537 KB
constexpr size_t WS_HNORM = 0;                          // [K] f32  0.5*||c||^2
constexpr size_t WS_COUNT = 8192;                       // [K] u32
constexpr size_t WS_BSUM  = 16384;                      // [1024] double
constexpr size_t WS_SW    = 24576;                      // [NTILE][4 slots][256 tid] half8, SLOT-MAJOR

__device__ inline unsigned long long pack_key(float d, int k) {
    unsigned u = __float_as_uint(d);
    u = (u & 0x80000000u) ? ~u : (u | 0x80000000u);   // monotone float->uint
    return ((unsigned long long)u << 32) | (unsigned)k;
}

__device__ inline float unpack_dist(unsigned long long key) {
    unsigned u = (unsigned)(key >> 32);
    u = (u & 0x80000000u) ? (u & 0x7FFFFFFFu) : ~u;   // inverse monotone map
    return __uint_as_float(u);
}

__device__ inline unsigned long long shfl_xor_u64_w16(unsigned long long v, int m) {
    int lo = __shfl_xor((int)(unsigned)v, m, 16);
    int hi = __shfl_xor((int)(unsigned)(v >> 32), m, 16);
    return ((unsigned long long)(unsigned)hi << 32) | (unsigned)lo;
}

// One thread per (code row r, 8-elem chunk c0). SLOT-MAJOR frag image:
//   sw[((t*4 + slot)*256 + tid]   (half8 units; one 4 KB plane per slot)
// Consumer tid = w*64 + l (g=l>>4, m16=l&15, code = t*64 + w*16 + m16) reads
// slots {0,1,2,3} = {hi chunk g, hi chunk g+4, lo chunk g, lo chunk g+4} at
// entry tid of each plane -> every B-load is 64 lanes x contiguous 16 B
// (fully coalesced, 16 cache lines/wave vs 64 for the old tid-major image;
// the TA line-throughput wall was the R1-R7 invariant ~70 us).
// Producer (r, c0): slot = c0>>2 (hi) / 2+(c0>>2) (lo), entry = w*64 + (c0&3)*16 + m16.
__global__ __launch_bounds__(256) void vq_init(const float* __restrict__ emb,
                                               float* __restrict__ hnorm,
                                               unsigned* __restrict__ counts,
                                               double* __restrict__ blocksums,
                                               half8* __restrict__ sw) {
    const int g  = blockIdx.x * 256 + threadIdx.x;   // 0..16383
    const int r  = g >> 3;                           // code row
    const int c0 = g & 7;                            // chunk within row
    const float4* p4 = (const float4*)(emb + (size_t)r * D + 8 * c0);
    float4 q0 = p4[0], q1 = p4[1];
    float v[8] = {q0.x, q0.y, q0.z, q0.w, q1.x, q1.y, q1.z, q1.w};
    half8 h, l;
    float s = 0.f;
#pragma unroll
    for (int i = 0; i < 8; ++i) {
        s += v[i] * v[i];
        _Float16 hh = (_Float16)v[i];
        h[i] = hh;
        l[i] = (_Float16)(v[i] - (float)hh);
    }
    const int t    = r >> 6;
    const int w    = (r >> 4) & 3;
    const int m16  = r & 15;
    const int entry = w * 64 + (c0 & 3) * 16 + m16;
    const int slot  = c0 >> 2;
    sw[((size_t)(t * 4 + slot)) * 256 + entry]     = h;   // hi plane
    sw[((size_t)(t * 4 + 2 + slot)) * 256 + entry] = l;   // lo plane

#pragma unroll
    for (int off = 1; off < 8; off <<= 1) s += __shfl_xor(s, off, 8);
    if (c0 == 0) hnorm[r] = 0.5f * s;
    if (g < K) counts[g] = 0u;
    if (g < NBLK) blocksums[g] = 0.0;
}

// Load one tile's 4 B fragments (one per 4 KB slot plane, each fully
// coalesced) + code half-norm into a named set. pb = sw + tid.
#define LOADB(TOFF, P0, P1, P2, P3, HN)                                            \
  {                                                                                \
    const half8* _q = pb + (TOFF) * 1024;                                          \
    P0 = _q[0]; P1 = _q[256]; P2 = _q[512]; P3 = _q[768];                          \
    HN = ph[(TOFF) * 64];                                                          \
  }

// 6 chained MFMAs into ONE accumulator initialized with hn. MFMAs batched
// under setprio(1). Min-tracking packs the tile index into the 5 low
// mantissa bits (2 VALU/elem; perturbation <= 32 ulp ~ 1.2e-4 << belt).
#define VQ_STEP(P0, P1, P2, P3, HN, TT)                                            \
  {                                                                                \
    f32x4 acc[4];                                                                  \
    __builtin_amdgcn_s_setprio(1);                                                 \
    _Pragma("unroll")                                                              \
    for (int a = 0; a < 4; ++a) {                                                  \
      acc[a] = (f32x4){(HN), (HN), (HN), (HN)};                                    \
      acc[a] = __builtin_amdgcn_mfma_f32_16x16x32_f16(axh[a][0], P0, acc[a], 0, 0, 0); \
      acc[a] = __builtin_amdgcn_mfma_f32_16x16x32_f16(axh[a][1], P1, acc[a], 0, 0, 0); \
      acc[a] = __builtin_amdgcn_mfma_f32_16x16x32_f16(axl[a][0], P0, acc[a], 0, 0, 0); \
      acc[a] = __builtin_amdgcn_mfma_f32_16x16x32_f16(axl[a][1], P1, acc[a], 0, 0, 0); \
      acc[a] = __builtin_amdgcn_mfma_f32_16x16x32_f16(axh[a][0], P2, acc[a], 0, 0, 0); \
      acc[a] = __builtin_amdgcn_mfma_f32_16x16x32_f16(axh[a][1], P3, acc[a], 0, 0, 0); \
    }                                                                              \
    __builtin_amdgcn_s_setprio(0);                                                 \
    _Pragma("unroll")                                                              \
    for (int a = 0; a < 4; ++a)                                                    \
      _Pragma("unroll")                                                            \
      for (int r = 0; r < 4; ++r) {                                                \
        unsigned _kb = (__float_as_uint(acc[a][r]) & 0xFFFFFFE0u) | (unsigned)(TT);\
        best_d[a][r] = fminf(best_d[a][r], __uint_as_float(_kb));                  \
      }                                                                            \
  }

// Fused: one block = 64 tokens x ALL 2048 codes. Barrier-free main loop,
// THREE-buffer rotating register pipeline (unroll-3, fixed set names): each
// tile's coalesced global->VGPR loads issued two full VQ_STEPs before use.
// No LDS in the hot loop, no fences, no launch_bounds occupancy hint.
__global__ __launch_bounds__(256) void vq_fused(const float* __restrict__ x,
                                                const float* __restrict__ emb,
                                                const float* __restrict__ hnorm,
                                                const half8* __restrict__ sw,
                                                unsigned* __restrict__ counts,
                                                double* __restrict__ blocksums,
                                                float* __restrict__ out) {
    __shared__ unsigned long long kls[64][5];         // 4 candidates + pad
    __shared__ int bks[64];
    __shared__ double wsum[4];

    const int tid  = threadIdx.x;
    const int lane = tid & 63;
    const int wav  = tid >> 6;
    const int t0   = blockIdx.x * TOK_PER_BLK;
    const int m16  = lane & 15;             // A row (token) / B col (code)
    const int g    = lane >> 4;             // k-chunk group (0..3)
    const int ko   = g * 8;
    const int cit  = wav * 16 + m16;        // wave w owns codes [w*16, w*16+16)

    // A fragments: 4 a-tiles (the block's 64 tokens), negated hi/lo fp16 split
    half8 axh[4][2], axl[4][2];
#pragma unroll
    for (int a = 0; a < 4; ++a) {
        const float* xr = x + (size_t)(t0 + 16 * a + m16) * D;
#pragma unroll
        for (int c = 0; c < 2; ++c) {
            const float4* p4 = (const float4*)(xr + 32 * c + ko);
            float4 q0 = p4[0], q1 = p4[1];
            float v[8] = {q0.x, q0.y, q0.z, q0.w, q1.x, q1.y, q1.z, q1.w};
            half8 h, l;
#pragma unroll
            for (int j = 0; j < 8; ++j) {
                float nv = -v[j];
                _Float16 hh = (_Float16)nv;
                h[j] = hh;
                l[j] = (_Float16)(nv - (float)hh);
            }
            axh[a][c] = h; axl[a][c] = l;
        }
    }

    float best_d[4][4];                     // packed keys: dist w/ tile idx in low 5 bits
#pragma unroll
    for (int a = 0; a < 4; ++a)
#pragma unroll
        for (int r = 0; r < 4; ++r) best_d[a][r] = FLT_MAX;

    // per-lane streaming pointers: one half8 per slot plane per tile
    const half8* pb = sw + (size_t)tid;               // tile stride = 1024 half8
    const float* ph = hnorm + cit;                    // tile stride = 64 floats

    half8 sA0, sA1, sA2, sA3;  float hA;   // set S0: tiles t = 0 mod 3
    half8 sB0, sB1, sB2, sB3;  float hB;   // set S1: tiles t = 1 mod 3
    half8 sC0, sC1, sC2, sC3;  float hC;   // set S2: tiles t = 2 mod 3

    // prologue: tiles 0,1 in flight
    LOADB(0, sA0, sA1, sA2, sA3, hA);
    LOADB(1, sB0, sB1, sB2, sB3, hB);

    // main loop: t = 0,3,...,27 (processes tiles 0..29; loads through 31, unguarded)
    for (int t = 0; t < 28; t += 3) {
        LOADB(2, sC0, sC1, sC2, sC3, hC);             // tile t+2, used 2 steps later
        VQ_STEP(sA0, sA1, sA2, sA3, hA, t);
        LOADB(3, sA0, sA1, sA2, sA3, hA);             // tile t+3
        VQ_STEP(sB0, sB1, sB2, sB3, hB, t + 1);
        LOADB(4, sB0, sB1, sB2, sB3, hB);             // tile t+4
        VQ_STEP(sC0, sC1, sC2, sC3, hC, t + 2);
        pb += 3 * 1024; ph += 3 * 64;
    }
    // tail: tiles 30 (in S0), 31 (in S1)
    VQ_STEP(sA0, sA1, sA2, sA3, hA, 30);
    VQ_STEP(sB0, sB1, sB2, sB3, hB, 31);

    // recover code from packed key; col-reduce over this wave's 16 columns
#pragma unroll
    for (int a = 0; a < 4; ++a)
#pragma unroll
        for (int r = 0; r < 4; ++r) {
            const unsigned bits = __float_as_uint(best_d[a][r]);
            const int code = (int)(bits & 31u) * TILE_C + cit;
            unsigned long long key = pack_key(best_d[a][r], code);
#pragma unroll
            for (int off = 8; off; off >>= 1) {
                unsigned long long o = shfl_xor_u64_w16(key, off);
                if (o < key) key = o;
            }
            if (m16 == 0) kls[16 * a + g * 4 + r][wav] = key;
        }
    __syncthreads();

    // merge the 4 wave-winners per token (wave 0, one lane per token)
    if (tid < 64) {
        float ds[4]; int kk[4];
        unsigned long long kmin = ~0ULL;
#pragma unroll
        for (int w = 0; w < 4; ++w) {
            unsigned long long key = kls[tid][w];
            ds[w] = unpack_dist(key);
            kk[w] = (int)(unsigned)(key & 0xFFFFFFFFu);
            if (key < kmin) kmin = key;
        }
        int bk = (int)(unsigned)(kmin & 0xFFFFFFFFu);
        const float fmin = unpack_dist(kmin);
        int cnt = 0;
#pragma unroll
        for (int w = 0; w < 4; ++w) cnt += (ds[w] <= fmin + EPS_RESCORE) ? 1 : 0;

        if (cnt > 1) {   // rare near-tie: exact fp32 rescore; packed-key min
            unsigned long long bkey = ~0ULL;   // smaller dist, tie smaller k
            const float* xr = x + (size_t)(t0 + tid) * D;
            for (int w = 0; w < 4; ++w) {
                if (ds[w] <= fmin + EPS_RESCORE) {
                    const int k = kk[w];
                    const float* cr = emb + (size_t)k * D;
                    float s0 = 0.f, s1 = 0.f, s2 = 0.f, s3 = 0.f;
#pragma unroll
                    for (int i = 0; i < 16; ++i) {
                        s0 = fmaf(cr[4 * i + 0], xr[4 * i + 0], s0);
                        s1 = fmaf(cr[4 * i + 1], xr[4 * i + 1], s1);
                        s2 = fmaf(cr[4 * i + 2], xr[4 * i + 2], s2);
                        s3 = fmaf(cr[4 * i + 3], xr[4 * i + 3], s3);
                    }
                    float hd = hnorm[k] - ((s0 + s1) + (s2 + s3));
                    unsigned long long key = pack_key(hd, k);
                    if (key < bkey) bkey = key;
                }
            }
            bk = (int)(unsigned)(bkey & 0xFFFFFFFFu);
        }
        bks[tid] = bk;
        out[IDX_OFF + t0 + tid] = (float)bk;
        atomicAdd(&counts[bk], 1u);
    }
    __syncthreads();

    // inline epilogue: quantize + sumsq (4 threads per token, coalesced)
    const int tok = tid >> 2;
    const int i4  = tid & 3;
    const int bk  = bks[tok];
    const float4* xr4 = (const float4*)(x + (size_t)(t0 + tok) * D);
    const float4* cr4 = (const float4*)(emb + (size_t)bk * D);
    float4* qr4 = (float4*)(out + (size_t)(t0 + tok) * D);
    float local = 0.f;
#pragma unroll
    for (int ii = 0; ii < 4; ++ii) {
        const int idx = i4 + 4 * ii;
        float4 xv = xr4[idx];
        float4 cv = cr4[idx];
        float dx = cv.x - xv.x, dy = cv.y - xv.y;
        float dz = cv.z - xv.z, dw = cv.w - xv.w;
        local += dx * dx + dy * dy + dz * dz + dw * dw;
        float4 q;
        q.x = xv.x + dx; q.y = xv.y + dy;   // straight-through: x + (q - x)
        q.z = xv.z + dz; q.w = xv.w + dw;
        qr4[idx] = q;
    }
    double ld = (double)local;
#pragma unroll
    for (int off = 32; off > 0; off >>= 1) ld += __shfl_down(ld, off, 64);
    if (lane == 0) wsum[wav] = ld;
    __syncthreads();
    if (tid == 0)
        blocksums[blockIdx.x] = (wsum[0] + wsum[1]) + (wsum[2] + wsum[3]);
}

__global__ __launch_bounds__(256) void vq_finalize(const unsigned* __restrict__ counts,
                                                   const double* __restrict__ blocksums,
                                                   float* __restrict__ out) {
    const int tid = threadIdx.x;
    double e = 0.0;
#pragma unroll
    for (int i = 0; i < 8; ++i) {
        int k = tid + i * 256;
        float p = (float)counts[k] / 65536.0f;
        out[PROB_OFF + k] = p;
        double pd = (double)p;
        e += pd * log(pd + 1e-5);
    }
    double s = 0.0;
#pragma unroll
    for (int i = 0; i < NBLK / 256; ++i) s += blocksums[tid + i * 256];
#pragma unroll
    for (int off = 32; off > 0; off >>= 1) {
        e += __shfl_down(e, off, 64);
        s += __shfl_down(s, off, 64);
    }
    __shared__ double we[4], ws2[4];
    int lane = tid & 63, wid = tid >> 6;
    if (lane == 0) { we[wid] = e; ws2[wid] = s; }
    __syncthreads();
    if (tid == 0) {
        double entropy = (we[0] + we[1]) + (we[2] + we[3]);
        double sumsq   = (ws2[0] + ws2[1]) + (ws2[2] + ws2[3]);
        double mse     = sumsq / (double)((size_t)N_TOK * D);
        out[SCAL_OFF + 0] = (float)(1.25 * mse + 0.1 * entropy); // vq_loss
        out[SCAL_OFF + 1] = (float)mse;                          // commitment_loss
        out[SCAL_OFF + 2] = (float)mse;                          // codebook_loss
        out[SCAL_OFF + 3] = (float)exp(-entropy);                // perplexity
        out[SCAL_OFF + 4] = (float)entropy;                      // entropy_loss
    }
}

extern "C" void kernel_launch(void* const* d_in, const int* in_sizes, int n_in,
                              void* d_out, int out_size, void* d_ws, size_t ws_size,
                              hipStream_t stream) {
    const float* x   = (const float*)d_in[0];
    const float* emb = (const float*)d_in[1];
    float* out = (float*)d_out;

    char* ws = (char*)d_ws;
    float*    hnorm     = (float*)(ws + WS_HNORM);
    unsigned* counts    = (unsigned*)(ws + WS_COUNT);
    double*   blocksums = (double*)(ws + WS_BSUM);
    half8*    sw        = (half8*)(ws + WS_SW);

    vq_init<<<K * 8 / 256, 256, 0, stream>>>(emb, hnorm, counts, blocksums, sw);
    vq_fused<<<NBLK, 256, 0, stream>>>(x, emb, hnorm, sw, counts, blocksums, out);
    vq_finalize<<<1, 256, 0, stream>>>(counts, blocksums, out);
}